// Round 1
// baseline (502.619 us; speedup 1.0000x reference)
//
#include <hip/hip_runtime.h>

#define T_LEN 800
#define B_SZ  16
#define D_IN  80
#define CCH   256
#define OUT_CH 222
#define HOPSZ 256
#define WINSZ 512
#define NFFT  1024
#define ZLEN  (T_LEN*HOPSZ)   // 204800
#define CSTRIDE 224           // padded ccep row stride

__device__ __forceinline__ float2 cmul(float2 a, float2 b){
    return make_float2(a.x*b.x - a.y*b.y, a.x*b.y + a.y*b.x);
}

// -------- conv1: x (B,T,80) -> h1 (B,T,256), relu --------
__global__ __launch_bounds__(256) void k_conv1(const float* __restrict__ x,
                                               const float* __restrict__ W,
                                               const float* __restrict__ bias,
                                               float* __restrict__ out){
    __shared__ __align__(16) float xs[80*20];   // [ci][tt], stride 20 (80B, 16B-aligned)
    const int t0 = blockIdx.x * 16;
    const int b  = blockIdx.y;
    const int tid = threadIdx.x;
    for (int i = tid; i < 80*18; i += 256){
        int tt = i / 80, ci = i - tt*80;
        int t = t0 - 1 + tt;
        xs[ci*20 + tt] = (t >= 0 && t < T_LEN) ? x[(b*T_LEN + t)*D_IN + ci] : 0.f;
    }
    __syncthreads();
    const int co = tid;
    float acc[16];
    float bv = bias[co];
    #pragma unroll
    for (int t = 0; t < 16; ++t) acc[t] = bv;
    for (int ci = 0; ci < 80; ++ci){
        const float* wp = &W[(co*80 + ci)*3];
        float w0 = wp[0], w1 = wp[1], w2 = wp[2];
        const float* xp = &xs[ci*20];
        float xr[18];
        #pragma unroll
        for (int q = 0; q < 4; ++q){
            float4 v = *(const float4*)(xp + 4*q);
            xr[4*q] = v.x; xr[4*q+1] = v.y; xr[4*q+2] = v.z; xr[4*q+3] = v.w;
        }
        { float2 v = *(const float2*)(xp + 16); xr[16] = v.x; xr[17] = v.y; }
        #pragma unroll
        for (int t = 0; t < 16; ++t)
            acc[t] += xr[t]*w0 + xr[t+1]*w1 + xr[t+2]*w2;
    }
    #pragma unroll
    for (int t = 0; t < 16; ++t)
        out[(b*T_LEN + t0 + t)*CCH + co] = fmaxf(acc[t], 0.f);
}

// -------- grouped conv (256->256, groups=8, Cin_g=32), relu --------
__global__ __launch_bounds__(256) void k_convg(const float* __restrict__ in,
                                               const float* __restrict__ W,
                                               const float* __restrict__ bias,
                                               float* __restrict__ out){
    __shared__ __align__(16) float hs[256*20];  // [ci][tt]
    const int t0 = blockIdx.x * 16;
    const int b  = blockIdx.y;
    const int tid = threadIdx.x;
    for (int i = tid; i < 256*18; i += 256){
        int tt = i >> 8, ci = i & 255;
        int t = t0 - 1 + tt;
        hs[ci*20 + tt] = (t >= 0 && t < T_LEN) ? in[(b*T_LEN + t)*CCH + ci] : 0.f;
    }
    __syncthreads();
    const int co = tid;
    const int cbase = (co >> 5) << 5;
    float acc[16];
    float bv = bias[co];
    #pragma unroll
    for (int t = 0; t < 16; ++t) acc[t] = bv;
    for (int cil = 0; cil < 32; ++cil){
        const float* wp = &W[(co*32 + cil)*3];
        float w0 = wp[0], w1 = wp[1], w2 = wp[2];
        const float* xp = &hs[(cbase + cil)*20];
        float xr[18];
        #pragma unroll
        for (int q = 0; q < 4; ++q){
            float4 v = *(const float4*)(xp + 4*q);
            xr[4*q] = v.x; xr[4*q+1] = v.y; xr[4*q+2] = v.z; xr[4*q+3] = v.w;
        }
        { float2 v = *(const float2*)(xp + 16); xr[16] = v.x; xr[17] = v.y; }
        #pragma unroll
        for (int t = 0; t < 16; ++t)
            acc[t] += xr[t]*w0 + xr[t+1]*w1 + xr[t+2]*w2;
    }
    #pragma unroll
    for (int t = 0; t < 16; ++t)
        out[(b*T_LEN + t0 + t)*CCH + co] = fmaxf(acc[t], 0.f);
}

// -------- conv4 (256->222) + divide by quefrency --------
__global__ __launch_bounds__(256) void k_conv4(const float* __restrict__ in,
                                               const float* __restrict__ W,
                                               const float* __restrict__ bias,
                                               float* __restrict__ ccep){
    __shared__ __align__(16) float hs[256*20];
    const int t0 = blockIdx.x * 16;
    const int b  = blockIdx.y;
    const int tid = threadIdx.x;
    for (int i = tid; i < 256*18; i += 256){
        int tt = i >> 8, ci = i & 255;
        int t = t0 - 1 + tt;
        hs[ci*20 + tt] = (t >= 0 && t < T_LEN) ? in[(b*T_LEN + t)*CCH + ci] : 0.f;
    }
    __syncthreads();
    const int co = tid;
    if (co >= OUT_CH) return;
    float acc[16];
    float bv = bias[co];
    #pragma unroll
    for (int t = 0; t < 16; ++t) acc[t] = bv;
    for (int ci = 0; ci < 256; ++ci){
        const float* wp = &W[(co*256 + ci)*3];
        float w0 = wp[0], w1 = wp[1], w2 = wp[2];
        const float* xp = &hs[ci*20];
        float xr[18];
        #pragma unroll
        for (int q = 0; q < 4; ++q){
            float4 v = *(const float4*)(xp + 4*q);
            xr[4*q] = v.x; xr[4*q+1] = v.y; xr[4*q+2] = v.z; xr[4*q+3] = v.w;
        }
        { float2 v = *(const float2*)(xp + 16); xr[16] = v.x; xr[17] = v.y; }
        #pragma unroll
        for (int t = 0; t < 16; ++t)
            acc[t] += xr[t]*w0 + xr[t+1]*w1 + xr[t+2]*w2;
    }
    float q = (co < 111) ? (float)(111 - co) : (float)(co - 110);
    float invq = 1.0f / q;
    #pragma unroll
    for (int t = 0; t < 16; ++t)
        ccep[(b*T_LEN + t0 + t)*CSTRIDE + co] = acc[t] * invq;
}

// -------- per-(b,t): FFT -> H -> IFFT -> imp; direct correlation; window --------
__global__ __launch_bounds__(256) void k_filter(const float* __restrict__ ccep,
                                                const float* __restrict__ z,
                                                float* __restrict__ zw){
    __shared__ __align__(16) float2 A[1024];    // 8 KB
    __shared__ __align__(16) float2 Bb[1024];   // 8 KB (reused as partial sums)
    __shared__ __align__(16) float2 Wt[512];    // twiddles exp(-2pi i j/1024)
    __shared__ __align__(16) float  imp[1024];  // swizzled impulse response
    __shared__ __align__(16) float  fr[512];    // frame of z
    const int t = blockIdx.x;
    const int b = blockIdx.y;
    const int tid = threadIdx.x;
    const float PI2 = 6.283185307179586f;

    // twiddle table
    for (int j = tid; j < 512; j += 256){
        float s, c;
        sincosf(-PI2 * (float)j * (1.0f/1024.0f), &s, &c);
        Wt[j] = make_float2(c, s);
    }
    // load padded ccep (bit-reversed positions) ; pad = 401
    const float* crow = &ccep[(b*T_LEN + t)*CSTRIDE];
    for (int i = tid; i < 1024; i += 256){
        float v = (i >= 401 && i < 623) ? crow[i - 401] : 0.f;
        int r = __brev((unsigned)i) >> 22;
        A[r] = make_float2(v, 0.f);
    }
    // load frame:  fr[k] = z[b, t*HOP + k - 255]  (zero outside)
    for (int k = tid; k < 512; k += 256){
        int zi = t*HOPSZ + k - 255;
        fr[k] = (zi >= 0 && zi < ZLEN) ? z[b*ZLEN + zi] : 0.f;
    }
    __syncthreads();

    // forward FFT (DIT, input bit-reversed -> natural order)
    for (int s = 1; s <= 10; ++s){
        int half = 1 << (s-1);
        #pragma unroll
        for (int r = 0; r < 2; ++r){
            int bidx = tid + (r << 8);
            int j = bidx & (half - 1);
            int g = bidx >> (s - 1);
            int i1 = (g << s) + j;
            int i2 = i1 + half;
            float2 tw = Wt[j << (10 - s)];
            float2 u = A[i1], v = A[i2];
            float2 vv = cmul(v, tw);
            A[i1] = make_float2(u.x + vv.x, u.y + vv.y);
            A[i2] = make_float2(u.x - vv.x, u.y - vv.y);
        }
        __syncthreads();
    }

    // H = 10^(Re/10) * exp(i*Im), written bit-reversed into Bb
    const float LOG2_10_DIV10 = 0.33219280948873623f;
    for (int i = tid; i < 1024; i += 256){
        float2 y = A[i];
        float mag = exp2f(y.x * LOG2_10_DIV10);
        float s, c;
        sincosf(y.y, &s, &c);
        int r = __brev((unsigned)i) >> 22;
        Bb[r] = make_float2(mag*c, mag*s);
    }
    __syncthreads();

    // inverse FFT (conjugate twiddles), scale 1/N at extraction
    for (int s = 1; s <= 10; ++s){
        int half = 1 << (s-1);
        #pragma unroll
        for (int r = 0; r < 2; ++r){
            int bidx = tid + (r << 8);
            int j = bidx & (half - 1);
            int g = bidx >> (s - 1);
            int i1 = (g << s) + j;
            int i2 = i1 + half;
            float2 t2 = Wt[j << (10 - s)];
            float2 tw = make_float2(t2.x, -t2.y);
            float2 u = Bb[i1], v = Bb[i2];
            float2 vv = cmul(v, tw);
            Bb[i1] = make_float2(u.x + vv.x, u.y + vv.y);
            Bb[i2] = make_float2(u.x - vv.x, u.y - vv.y);
        }
        __syncthreads();
    }

    // extract imp (real part, 1/1024), 4-dword-block XOR swizzle for bank spread
    for (int i = tid; i < 1024; i += 256){
        int blk = i >> 2, off = i & 3;
        int sb = blk ^ ((blk >> 3) & 7);
        imp[(sb << 2) + off] = Bb[i].x * (1.0f/1024.0f);
    }
    __syncthreads();

    // correlation: C[n] = sum_k fr[k] * imp[k + 511 - n]
    // wave w handles k in [w*128, w*128+128); lane owns 8 consecutive n (n0=8*lane)
    const int w  = tid >> 6;
    const int l  = tid & 63;
    const int n0 = l << 3;
    float acc[8];
    #pragma unroll
    for (int i = 0; i < 8; ++i) acc[i] = 0.f;
    const int kbeg = w * 128;
    for (int k0 = kbeg; k0 < kbeg + 128; k0 += 8){
        float4 f0 = *(const float4*)&fr[k0];
        float4 f1 = *(const float4*)&fr[k0 + 4];
        int jb = (k0 + 504 - n0) >> 2;        // window base block (16B aligned)
        float im16[16];
        #pragma unroll
        for (int c = 0; c < 4; ++c){
            int jc = jb + c;
            int sb = jc ^ ((jc >> 3) & 7);
            float4 v = *(const float4*)&imp[sb << 2];
            im16[4*c] = v.x; im16[4*c+1] = v.y; im16[4*c+2] = v.z; im16[4*c+3] = v.w;
        }
        float fj[8] = {f0.x, f0.y, f0.z, f0.w, f1.x, f1.y, f1.z, f1.w};
        #pragma unroll
        for (int j = 0; j < 8; ++j)
            #pragma unroll
            for (int i = 0; i < 8; ++i)
                acc[i] += fj[j] * im16[j + 7 - i];   // imp[(k0+j)+511-(n0+i)]
    }
    float* part = (float*)Bb;   // 2048 floats, Bb no longer needed
    #pragma unroll
    for (int i = 0; i < 8; ++i) part[w*512 + n0 + i] = acc[i];
    __syncthreads();

    // reduce 4 wave-partials, apply Hann window, store zw
    float* zrow = &zw[(size_t)(b*T_LEN + t)*512];
    for (int n = tid; n < 512; n += 256){
        float ssum = part[n] + part[512 + n] + part[1024 + n] + part[1536 + n];
        float wv = 0.5f * (1.0f - __cosf(PI2 * (float)n * (1.0f/512.0f)));
        zrow[n] = ssum * wv;
    }
}

// -------- OLA + clip --------
__global__ __launch_bounds__(256) void k_ola(const float* __restrict__ zw,
                                             float* __restrict__ out){
    const int t = blockIdx.x;
    const int b = blockIdx.y;
    const int h = threadIdx.x;
    const int tm = (t + T_LEN - 1) % T_LEN;
    float v = zw[(size_t)(b*T_LEN + t)*512 + h]
            + zw[(size_t)(b*T_LEN + tm)*512 + 256 + h];
    v = fminf(fmaxf(v, -1.0f), 1.0f);
    out[(size_t)b*ZLEN + t*HOPSZ + h] = v;
}

extern "C" void kernel_launch(void* const* d_in, const int* in_sizes, int n_in,
                              void* d_out, int out_size, void* d_ws, size_t ws_size,
                              hipStream_t stream){
    const float* x  = (const float*)d_in[0];
    const float* z  = (const float*)d_in[1];
    const float* W1 = (const float*)d_in[2];
    const float* b1 = (const float*)d_in[3];
    const float* W2 = (const float*)d_in[4];
    const float* b2 = (const float*)d_in[5];
    const float* W3 = (const float*)d_in[6];
    const float* b3 = (const float*)d_in[7];
    const float* W4 = (const float*)d_in[8];
    const float* b4 = (const float*)d_in[9];
    float* out = (float*)d_out;
    float* ws  = (float*)d_ws;

    float* h1   = ws;                 // 3,276,800 floats
    float* h2   = ws + 3276800;       // 3,276,800 floats (ccep overlays this)
    float* ccep = h2;
    float* zwb  = ws + 6553600;       // 6,553,600 floats
    // total ws use: 13,107,200 floats = 52.4 MB

    dim3 blk(256);
    dim3 gconv(T_LEN/16, B_SZ);       // (50,16)
    dim3 gf(T_LEN, B_SZ);             // (800,16)

    k_conv1<<<gconv, blk, 0, stream>>>(x, W1, b1, h1);
    k_convg<<<gconv, blk, 0, stream>>>(h1, W2, b2, h2);
    k_convg<<<gconv, blk, 0, stream>>>(h2, W3, b3, h1);
    k_conv4<<<gconv, blk, 0, stream>>>(h1, W4, b4, ccep);
    k_filter<<<gf, blk, 0, stream>>>(ccep, z, zwb);
    k_ola<<<gf, blk, 0, stream>>>(zwb, out);
}

// Round 2
// 374.758 us; speedup vs baseline: 1.3412x; 1.3412x over previous
//
#include <hip/hip_runtime.h>

#define T_LEN 800
#define B_SZ  16
#define D_IN  80
#define CCH   256
#define OUT_CH 222
#define HOPSZ 256
#define WINSZ 512
#define NFFT  1024
#define ZLEN  (T_LEN*HOPSZ)   // 204800
#define CSTRIDE 224           // padded ccep row stride

#define PHI(i) ((i) + ((i)>>3))   // pad 1 per 8 complex: conflict-free strides

__device__ __forceinline__ float2 cmul(float2 a, float2 b){
    return make_float2(a.x*b.x - a.y*b.y, a.x*b.y + a.y*b.x);
}

// -------- conv1: x (B,T,80) -> h1 (B,T,256), relu --------
__global__ __launch_bounds__(256) void k_conv1(const float* __restrict__ x,
                                               const float* __restrict__ W,
                                               const float* __restrict__ bias,
                                               float* __restrict__ out){
    __shared__ __align__(16) float xs[80*20];
    const int t0 = blockIdx.x * 16;
    const int b  = blockIdx.y;
    const int tid = threadIdx.x;
    for (int i = tid; i < 80*18; i += 256){
        int tt = i / 80, ci = i - tt*80;
        int t = t0 - 1 + tt;
        xs[ci*20 + tt] = (t >= 0 && t < T_LEN) ? x[(b*T_LEN + t)*D_IN + ci] : 0.f;
    }
    __syncthreads();
    const int co = tid;
    float acc[16];
    float bv = bias[co];
    #pragma unroll
    for (int t = 0; t < 16; ++t) acc[t] = bv;
    for (int ci = 0; ci < 80; ++ci){
        const float* wp = &W[(co*80 + ci)*3];
        float w0 = wp[0], w1 = wp[1], w2 = wp[2];
        const float* xp = &xs[ci*20];
        float xr[18];
        #pragma unroll
        for (int q = 0; q < 4; ++q){
            float4 v = *(const float4*)(xp + 4*q);
            xr[4*q] = v.x; xr[4*q+1] = v.y; xr[4*q+2] = v.z; xr[4*q+3] = v.w;
        }
        { float2 v = *(const float2*)(xp + 16); xr[16] = v.x; xr[17] = v.y; }
        #pragma unroll
        for (int t = 0; t < 16; ++t)
            acc[t] += xr[t]*w0 + xr[t+1]*w1 + xr[t+2]*w2;
    }
    #pragma unroll
    for (int t = 0; t < 16; ++t)
        out[(b*T_LEN + t0 + t)*CCH + co] = fmaxf(acc[t], 0.f);
}

// -------- grouped conv (256->256, groups=8, Cin_g=32), relu --------
__global__ __launch_bounds__(256) void k_convg(const float* __restrict__ in,
                                               const float* __restrict__ W,
                                               const float* __restrict__ bias,
                                               float* __restrict__ out){
    __shared__ __align__(16) float hs[256*20];
    const int t0 = blockIdx.x * 16;
    const int b  = blockIdx.y;
    const int tid = threadIdx.x;
    for (int i = tid; i < 256*18; i += 256){
        int tt = i >> 8, ci = i & 255;
        int t = t0 - 1 + tt;
        hs[ci*20 + tt] = (t >= 0 && t < T_LEN) ? in[(b*T_LEN + t)*CCH + ci] : 0.f;
    }
    __syncthreads();
    const int co = tid;
    const int cbase = (co >> 5) << 5;
    float acc[16];
    float bv = bias[co];
    #pragma unroll
    for (int t = 0; t < 16; ++t) acc[t] = bv;
    for (int cil = 0; cil < 32; ++cil){
        const float* wp = &W[(co*32 + cil)*3];
        float w0 = wp[0], w1 = wp[1], w2 = wp[2];
        const float* xp = &hs[(cbase + cil)*20];
        float xr[18];
        #pragma unroll
        for (int q = 0; q < 4; ++q){
            float4 v = *(const float4*)(xp + 4*q);
            xr[4*q] = v.x; xr[4*q+1] = v.y; xr[4*q+2] = v.z; xr[4*q+3] = v.w;
        }
        { float2 v = *(const float2*)(xp + 16); xr[16] = v.x; xr[17] = v.y; }
        #pragma unroll
        for (int t = 0; t < 16; ++t)
            acc[t] += xr[t]*w0 + xr[t+1]*w1 + xr[t+2]*w2;
    }
    #pragma unroll
    for (int t = 0; t < 16; ++t)
        out[(b*T_LEN + t0 + t)*CCH + co] = fmaxf(acc[t], 0.f);
}

// -------- conv4 (256->222) + divide by quefrency --------
__global__ __launch_bounds__(256) void k_conv4(const float* __restrict__ in,
                                               const float* __restrict__ W,
                                               const float* __restrict__ bias,
                                               float* __restrict__ ccep){
    __shared__ __align__(16) float hs[256*20];
    const int t0 = blockIdx.x * 16;
    const int b  = blockIdx.y;
    const int tid = threadIdx.x;
    for (int i = tid; i < 256*18; i += 256){
        int tt = i >> 8, ci = i & 255;
        int t = t0 - 1 + tt;
        hs[ci*20 + tt] = (t >= 0 && t < T_LEN) ? in[(b*T_LEN + t)*CCH + ci] : 0.f;
    }
    __syncthreads();
    const int co = tid;
    if (co >= OUT_CH) return;
    float acc[16];
    float bv = bias[co];
    #pragma unroll
    for (int t = 0; t < 16; ++t) acc[t] = bv;
    for (int ci = 0; ci < 256; ++ci){
        const float* wp = &W[(co*256 + ci)*3];
        float w0 = wp[0], w1 = wp[1], w2 = wp[2];
        const float* xp = &hs[ci*20];
        float xr[18];
        #pragma unroll
        for (int q = 0; q < 4; ++q){
            float4 v = *(const float4*)(xp + 4*q);
            xr[4*q] = v.x; xr[4*q+1] = v.y; xr[4*q+2] = v.z; xr[4*q+3] = v.w;
        }
        { float2 v = *(const float2*)(xp + 16); xr[16] = v.x; xr[17] = v.y; }
        #pragma unroll
        for (int t = 0; t < 16; ++t)
            acc[t] += xr[t]*w0 + xr[t+1]*w1 + xr[t+2]*w2;
    }
    float q = (co < 111) ? (float)(111 - co) : (float)(co - 110);
    float invq = 1.0f / q;
    #pragma unroll
    for (int t = 0; t < 16; ++t)
        ccep[(b*T_LEN + t0 + t)*CSTRIDE + co] = acc[t] * invq;
}

// -------- radix-4 Stockham stage: 256 threads, one j each --------
template<int Ns, bool INV>
__device__ __forceinline__ void r4stage(const float2* __restrict__ src,
                                        float2* __restrict__ dst,
                                        const float2* __restrict__ Wt,
                                        int j){
    const int jm = j & (Ns - 1);
    float2 v0 = src[PHI(j)];
    float2 v1 = src[PHI(j + 256)];
    float2 v2 = src[PHI(j + 512)];
    float2 v3 = src[PHI(j + 768)];
    if (Ns > 1){
        float2 w1 = Wt[PHI(jm * (256 / Ns))];
        if (INV) w1.y = -w1.y;
        float2 w2 = cmul(w1, w1);
        float2 w3 = cmul(w2, w1);
        v1 = cmul(v1, w1);
        v2 = cmul(v2, w2);
        v3 = cmul(v3, w3);
    }
    float2 t0 = make_float2(v0.x + v2.x, v0.y + v2.y);
    float2 t1 = make_float2(v0.x - v2.x, v0.y - v2.y);
    float2 t2 = make_float2(v1.x + v3.x, v1.y + v3.y);
    float2 t3 = make_float2(v1.x - v3.x, v1.y - v3.y);
    float2 o0 = make_float2(t0.x + t2.x, t0.y + t2.y);
    float2 o2 = make_float2(t0.x - t2.x, t0.y - t2.y);
    float2 o1, o3;
    if (!INV){ // -i*t3 = (t3.y, -t3.x)
        o1 = make_float2(t1.x + t3.y, t1.y - t3.x);
        o3 = make_float2(t1.x - t3.y, t1.y + t3.x);
    } else {   // +i*t3 = (-t3.y, t3.x)
        o1 = make_float2(t1.x - t3.y, t1.y + t3.x);
        o3 = make_float2(t1.x + t3.y, t1.y - t3.x);
    }
    const int base = ((j - jm) << 2) + jm;
    dst[PHI(base)]          = o0;
    dst[PHI(base + Ns)]     = o1;
    dst[PHI(base + 2*Ns)]   = o2;
    dst[PHI(base + 3*Ns)]   = o3;
}

// -------- per-(b,t): FFT -> H -> IFFT -> imp; direct correlation; window --------
__global__ __launch_bounds__(256) void k_filter(const float* __restrict__ ccep,
                                                const float* __restrict__ z,
                                                float* __restrict__ zw){
    __shared__ __align__(16) float2 A[1152];    // padded 1024-complex buffer
    __shared__ __align__(16) float2 Bb[1152];   // ping-pong partner / partials
    __shared__ __align__(16) float2 Wt[288];    // W_1024^k, k<256 (padded)
    __shared__ __align__(16) float  fr[512];
    const int t = blockIdx.x;
    const int b = blockIdx.y;
    const int tid = threadIdx.x;
    const float PI2 = 6.283185307179586f;

    // twiddle table (one sincos per thread)
    {
        float s, c;
        sincosf(-PI2 * (float)tid * (1.0f/1024.0f), &s, &c);
        Wt[PHI(tid)] = make_float2(c, s);
    }
    // load padded ccep natural order; pad = 401
    const float* crow = &ccep[(b*T_LEN + t)*CSTRIDE];
    #pragma unroll
    for (int r = 0; r < 4; ++r){
        int i = tid + (r << 8);
        float v = (i >= 401 && i < 623) ? crow[i - 401] : 0.f;
        A[PHI(i)] = make_float2(v, 0.f);
    }
    // frame: fr[k] = z[b, t*HOP + k - 255]
    for (int k = tid; k < 512; k += 256){
        int zi = t*HOPSZ + k - 255;
        fr[k] = (zi >= 0 && zi < ZLEN) ? z[b*ZLEN + zi] : 0.f;
    }
    __syncthreads();

    // forward FFT (natural -> natural, Stockham)
    r4stage<1,  false>(A,  Bb, Wt, tid); __syncthreads();
    r4stage<4,  false>(Bb, A,  Wt, tid); __syncthreads();
    r4stage<16, false>(A,  Bb, Wt, tid); __syncthreads();
    r4stage<64, false>(Bb, A,  Wt, tid); __syncthreads();
    r4stage<256,false>(A,  Bb, Wt, tid); __syncthreads();

    // H = 10^(Re/10) * exp(i*Im), with 1/1024 IFFT scale folded in
    const float LOG2_10_DIV10 = 0.33219280948873623f;
    #pragma unroll
    for (int r = 0; r < 4; ++r){
        int i = tid + (r << 8);
        float2 y = Bb[PHI(i)];
        float mag = exp2f(y.x * LOG2_10_DIV10) * (1.0f/1024.0f);
        float s, c;
        sincosf(y.y, &s, &c);
        A[PHI(i)] = make_float2(mag*c, mag*s);
    }
    __syncthreads();

    // inverse FFT
    r4stage<1,  true>(A,  Bb, Wt, tid); __syncthreads();
    r4stage<4,  true>(Bb, A,  Wt, tid); __syncthreads();
    r4stage<16, true>(A,  Bb, Wt, tid); __syncthreads();
    r4stage<64, true>(Bb, A,  Wt, tid); __syncthreads();
    r4stage<256,true>(A,  Bb, Wt, tid); __syncthreads();

    // extract imp (real part) into A's storage, 4-dword-block XOR swizzle
    float* impf = (float*)A;
    #pragma unroll
    for (int r = 0; r < 4; ++r){
        int i = tid + (r << 8);
        float v = Bb[PHI(i)].x;
        int blk = i >> 2, off = i & 3;
        int sb = blk ^ ((blk >> 3) & 7);
        impf[(sb << 2) + off] = v;
    }
    __syncthreads();

    // correlation: C[n] = sum_k fr[k] * imp[k + 511 - n]
    // wave w: k in [128w, 128w+128); lane owns 8 consecutive n; rolling window
    {
        const int w  = tid >> 6;
        const int l  = tid & 63;
        const int n0 = l << 3;
        float acc[8];
        #pragma unroll
        for (int i = 0; i < 8; ++i) acc[i] = 0.f;
        const int kb = w << 7;
        int jb = (kb + 504 - n0) >> 2;
        float wlo[8], whi[8];
#define RD8(blk, dst) { \
        int _b0 = (blk), _b1 = (blk) + 1; \
        int _s0 = (_b0 ^ ((_b0 >> 3) & 7)) << 2; \
        int _s1 = (_b1 ^ ((_b1 >> 3) & 7)) << 2; \
        float4 _a  = *(const float4*)&impf[_s0]; \
        float4 _bv = *(const float4*)&impf[_s1]; \
        dst[0]=_a.x; dst[1]=_a.y; dst[2]=_a.z; dst[3]=_a.w; \
        dst[4]=_bv.x; dst[5]=_bv.y; dst[6]=_bv.z; dst[7]=_bv.w; }
        RD8(jb, wlo);
        #pragma unroll
        for (int it = 0; it < 8; ++it){
            int k0 = kb + (it << 4);
            RD8(jb + 2, whi);
            float4 f0 = *(const float4*)&fr[k0];
            float4 f1 = *(const float4*)&fr[k0 + 4];
            float fj[8] = {f0.x,f0.y,f0.z,f0.w,f1.x,f1.y,f1.z,f1.w};
            #pragma unroll
            for (int j = 0; j < 8; ++j){
                #pragma unroll
                for (int i = 0; i < 8; ++i){
                    int idx = j + 7 - i;
                    float iv = (idx < 8) ? wlo[idx] : whi[idx - 8];
                    acc[i] += fj[j] * iv;
                }
            }
            RD8(jb + 4, wlo);
            float4 g0 = *(const float4*)&fr[k0 + 8];
            float4 g1 = *(const float4*)&fr[k0 + 12];
            float gj[8] = {g0.x,g0.y,g0.z,g0.w,g1.x,g1.y,g1.z,g1.w};
            #pragma unroll
            for (int j = 0; j < 8; ++j){
                #pragma unroll
                for (int i = 0; i < 8; ++i){
                    int idx = j + 7 - i;
                    float iv = (idx < 8) ? whi[idx] : wlo[idx - 8];
                    acc[i] += gj[j] * iv;
                }
            }
            jb += 4;
        }
#undef RD8
        float* part = (float*)Bb;
        #pragma unroll
        for (int i = 0; i < 8; ++i) part[w*512 + n0 + i] = acc[i];
    }
    __syncthreads();

    // reduce 4 wave-partials, Hann window, store
    const float* part = (const float*)Bb;
    float* zrow = &zw[(size_t)(b*T_LEN + t)*512];
    for (int n = tid; n < 512; n += 256){
        float ssum = part[n] + part[512 + n] + part[1024 + n] + part[1536 + n];
        float wv = 0.5f * (1.0f - __cosf(PI2 * (float)n * (1.0f/512.0f)));
        zrow[n] = ssum * wv;
    }
}

// -------- OLA + clip --------
__global__ __launch_bounds__(256) void k_ola(const float* __restrict__ zw,
                                             float* __restrict__ out){
    const int t = blockIdx.x;
    const int b = blockIdx.y;
    const int h = threadIdx.x;
    const int tm = (t + T_LEN - 1) % T_LEN;
    float v = zw[(size_t)(b*T_LEN + t)*512 + h]
            + zw[(size_t)(b*T_LEN + tm)*512 + 256 + h];
    v = fminf(fmaxf(v, -1.0f), 1.0f);
    out[(size_t)b*ZLEN + t*HOPSZ + h] = v;
}

extern "C" void kernel_launch(void* const* d_in, const int* in_sizes, int n_in,
                              void* d_out, int out_size, void* d_ws, size_t ws_size,
                              hipStream_t stream){
    const float* x  = (const float*)d_in[0];
    const float* z  = (const float*)d_in[1];
    const float* W1 = (const float*)d_in[2];
    const float* b1 = (const float*)d_in[3];
    const float* W2 = (const float*)d_in[4];
    const float* b2 = (const float*)d_in[5];
    const float* W3 = (const float*)d_in[6];
    const float* b3 = (const float*)d_in[7];
    const float* W4 = (const float*)d_in[8];
    const float* b4 = (const float*)d_in[9];
    float* out = (float*)d_out;
    float* ws  = (float*)d_ws;

    float* h1   = ws;                 // 3,276,800 floats
    float* h2   = ws + 3276800;       // 3,276,800 floats (ccep overlays this)
    float* ccep = h2;
    float* zwb  = ws + 6553600;       // 6,553,600 floats

    dim3 blk(256);
    dim3 gconv(T_LEN/16, B_SZ);       // (50,16)
    dim3 gf(T_LEN, B_SZ);             // (800,16)

    k_conv1<<<gconv, blk, 0, stream>>>(x, W1, b1, h1);
    k_convg<<<gconv, blk, 0, stream>>>(h1, W2, b2, h2);
    k_convg<<<gconv, blk, 0, stream>>>(h2, W3, b3, h1);
    k_conv4<<<gconv, blk, 0, stream>>>(h1, W4, b4, ccep);
    k_filter<<<gf, blk, 0, stream>>>(ccep, z, zwb);
    k_ola<<<gf, blk, 0, stream>>>(zwb, out);
}

// Round 3
// 292.892 us; speedup vs baseline: 1.7161x; 1.2795x over previous
//
#include <hip/hip_runtime.h>

#define T_LEN 800
#define B_SZ  16
#define D_IN  80
#define CCH   256
#define OUT_CH 222
#define HOPSZ 256
#define WINSZ 512
#define NFFT  1024
#define ZLEN  (T_LEN*HOPSZ)   // 204800
#define CSTRIDE 224           // padded ccep row stride

#define PHI(i) ((i) + ((i)>>3))   // pad 1 per 8 complex: conflict-free strides

__device__ __forceinline__ float2 cmul(float2 a, float2 b){
    return make_float2(a.x*b.x - a.y*b.y, a.x*b.y + a.y*b.x);
}

// -------- conv1: x (B,T,80) -> h1 (B,T,256), relu --------
__global__ __launch_bounds__(256) void k_conv1(const float* __restrict__ x,
                                               const float* __restrict__ W,
                                               const float* __restrict__ bias,
                                               float* __restrict__ out){
    __shared__ __align__(16) float xs[80*20];
    const int t0 = blockIdx.x * 16;
    const int b  = blockIdx.y;
    const int tid = threadIdx.x;
    for (int i = tid; i < 80*18; i += 256){
        int tt = i / 80, ci = i - tt*80;
        int t = t0 - 1 + tt;
        xs[ci*20 + tt] = (t >= 0 && t < T_LEN) ? x[(b*T_LEN + t)*D_IN + ci] : 0.f;
    }
    __syncthreads();
    const int co = tid;
    float acc[16];
    float bv = bias[co];
    #pragma unroll
    for (int t = 0; t < 16; ++t) acc[t] = bv;
    for (int ci = 0; ci < 80; ++ci){
        const float* wp = &W[(co*80 + ci)*3];
        float w0 = wp[0], w1 = wp[1], w2 = wp[2];
        const float* xp = &xs[ci*20];
        float xr[18];
        #pragma unroll
        for (int q = 0; q < 4; ++q){
            float4 v = *(const float4*)(xp + 4*q);
            xr[4*q] = v.x; xr[4*q+1] = v.y; xr[4*q+2] = v.z; xr[4*q+3] = v.w;
        }
        { float2 v = *(const float2*)(xp + 16); xr[16] = v.x; xr[17] = v.y; }
        #pragma unroll
        for (int t = 0; t < 16; ++t)
            acc[t] += xr[t]*w0 + xr[t+1]*w1 + xr[t+2]*w2;
    }
    #pragma unroll
    for (int t = 0; t < 16; ++t)
        out[(b*T_LEN + t0 + t)*CCH + co] = fmaxf(acc[t], 0.f);
}

// -------- grouped conv (256->256, groups=8, Cin_g=32), relu --------
__global__ __launch_bounds__(256) void k_convg(const float* __restrict__ in,
                                               const float* __restrict__ W,
                                               const float* __restrict__ bias,
                                               float* __restrict__ out){
    __shared__ __align__(16) float hs[256*20];
    const int t0 = blockIdx.x * 16;
    const int b  = blockIdx.y;
    const int tid = threadIdx.x;
    for (int i = tid; i < 256*18; i += 256){
        int tt = i >> 8, ci = i & 255;
        int t = t0 - 1 + tt;
        hs[ci*20 + tt] = (t >= 0 && t < T_LEN) ? in[(b*T_LEN + t)*CCH + ci] : 0.f;
    }
    __syncthreads();
    const int co = tid;
    const int cbase = (co >> 5) << 5;
    float acc[16];
    float bv = bias[co];
    #pragma unroll
    for (int t = 0; t < 16; ++t) acc[t] = bv;
    for (int cil = 0; cil < 32; ++cil){
        const float* wp = &W[(co*32 + cil)*3];
        float w0 = wp[0], w1 = wp[1], w2 = wp[2];
        const float* xp = &hs[(cbase + cil)*20];
        float xr[18];
        #pragma unroll
        for (int q = 0; q < 4; ++q){
            float4 v = *(const float4*)(xp + 4*q);
            xr[4*q] = v.x; xr[4*q+1] = v.y; xr[4*q+2] = v.z; xr[4*q+3] = v.w;
        }
        { float2 v = *(const float2*)(xp + 16); xr[16] = v.x; xr[17] = v.y; }
        #pragma unroll
        for (int t = 0; t < 16; ++t)
            acc[t] += xr[t]*w0 + xr[t+1]*w1 + xr[t+2]*w2;
    }
    #pragma unroll
    for (int t = 0; t < 16; ++t)
        out[(b*T_LEN + t0 + t)*CCH + co] = fmaxf(acc[t], 0.f);
}

// -------- conv4 (256->222) + divide by quefrency --------
__global__ __launch_bounds__(256) void k_conv4(const float* __restrict__ in,
                                               const float* __restrict__ W,
                                               const float* __restrict__ bias,
                                               float* __restrict__ ccep){
    __shared__ __align__(16) float hs[256*20];
    const int t0 = blockIdx.x * 16;
    const int b  = blockIdx.y;
    const int tid = threadIdx.x;
    for (int i = tid; i < 256*18; i += 256){
        int tt = i >> 8, ci = i & 255;
        int t = t0 - 1 + tt;
        hs[ci*20 + tt] = (t >= 0 && t < T_LEN) ? in[(b*T_LEN + t)*CCH + ci] : 0.f;
    }
    __syncthreads();
    const int co = tid;
    if (co >= OUT_CH) return;
    float acc[16];
    float bv = bias[co];
    #pragma unroll
    for (int t = 0; t < 16; ++t) acc[t] = bv;
    for (int ci = 0; ci < 256; ++ci){
        const float* wp = &W[(co*256 + ci)*3];
        float w0 = wp[0], w1 = wp[1], w2 = wp[2];
        const float* xp = &hs[ci*20];
        float xr[18];
        #pragma unroll
        for (int q = 0; q < 4; ++q){
            float4 v = *(const float4*)(xp + 4*q);
            xr[4*q] = v.x; xr[4*q+1] = v.y; xr[4*q+2] = v.z; xr[4*q+3] = v.w;
        }
        { float2 v = *(const float2*)(xp + 16); xr[16] = v.x; xr[17] = v.y; }
        #pragma unroll
        for (int t = 0; t < 16; ++t)
            acc[t] += xr[t]*w0 + xr[t+1]*w1 + xr[t+2]*w2;
    }
    float q = (co < 111) ? (float)(111 - co) : (float)(co - 110);
    float invq = 1.0f / q;
    #pragma unroll
    for (int t = 0; t < 16; ++t)
        ccep[(b*T_LEN + t0 + t)*CSTRIDE + co] = acc[t] * invq;
}

// -------- radix-4 Stockham stage: 256 threads, one j each --------
template<int Ns, bool INV>
__device__ __forceinline__ void r4stage(const float2* __restrict__ src,
                                        float2* __restrict__ dst,
                                        const float2* __restrict__ Wt,
                                        int j){
    const int jm = j & (Ns - 1);
    float2 v0 = src[PHI(j)];
    float2 v1 = src[PHI(j + 256)];
    float2 v2 = src[PHI(j + 512)];
    float2 v3 = src[PHI(j + 768)];
    if (Ns > 1){
        float2 w1 = Wt[PHI(jm * (256 / Ns))];
        if (INV) w1.y = -w1.y;
        float2 w2 = cmul(w1, w1);
        float2 w3 = cmul(w2, w1);
        v1 = cmul(v1, w1);
        v2 = cmul(v2, w2);
        v3 = cmul(v3, w3);
    }
    float2 t0 = make_float2(v0.x + v2.x, v0.y + v2.y);
    float2 t1 = make_float2(v0.x - v2.x, v0.y - v2.y);
    float2 t2 = make_float2(v1.x + v3.x, v1.y + v3.y);
    float2 t3 = make_float2(v1.x - v3.x, v1.y - v3.y);
    float2 o0 = make_float2(t0.x + t2.x, t0.y + t2.y);
    float2 o2 = make_float2(t0.x - t2.x, t0.y - t2.y);
    float2 o1, o3;
    if (!INV){ // -i*t3
        o1 = make_float2(t1.x + t3.y, t1.y - t3.x);
        o3 = make_float2(t1.x - t3.y, t1.y + t3.x);
    } else {   // +i*t3
        o1 = make_float2(t1.x - t3.y, t1.y + t3.x);
        o3 = make_float2(t1.x + t3.y, t1.y - t3.x);
    }
    const int base = ((j - jm) << 2) + jm;
    dst[PHI(base)]          = o0;
    dst[PHI(base + Ns)]     = o1;
    dst[PHI(base + 2*Ns)]   = o2;
    dst[PHI(base + 3*Ns)]   = o3;
}

// -------- per-(b,t): packed FFT(ccep,frame) -> G = conj(F)*H -> IFFT -> window --------
__global__ __launch_bounds__(256) void k_filter(const float* __restrict__ ccep,
                                                const float* __restrict__ z,
                                                float* __restrict__ zw){
    __shared__ __align__(16) float2 A[1152];
    __shared__ __align__(16) float2 Bb[1152];
    __shared__ __align__(16) float2 Wt[288];
    const int t = blockIdx.x;
    const int b = blockIdx.y;
    const int tid = threadIdx.x;
    const float PI2 = 6.283185307179586f;

    // twiddle table (one sincos per thread)
    {
        float s, c;
        sincosf(-PI2 * (float)tid * (1.0f/1024.0f), &s, &c);
        Wt[PHI(tid)] = make_float2(c, s);
    }
    // packed load: p[i] = ccep_pad[i] + i*frame_pad[i]
    //   ccep_pad[i] = crow[i-401] for i in [401,623), else 0
    //   frame_pad[i] = z[b, t*HOP + i - 255] for i in [0,512), else 0
    const float* crow = &ccep[(b*T_LEN + t)*CSTRIDE];
    #pragma unroll
    for (int r = 0; r < 4; ++r){
        int i = tid + (r << 8);
        float av = (i >= 401 && i < 623) ? crow[i - 401] : 0.f;
        float fv = 0.f;
        if (i < 512){
            int zi = t*HOPSZ + i - 255;
            fv = (zi >= 0 && zi < ZLEN) ? z[b*ZLEN + zi] : 0.f;
        }
        A[PHI(i)] = make_float2(av, fv);
    }
    __syncthreads();

    // forward FFT (natural -> natural, Stockham), result in Bb
    r4stage<1,  false>(A,  Bb, Wt, tid); __syncthreads();
    r4stage<4,  false>(Bb, A,  Wt, tid); __syncthreads();
    r4stage<16, false>(A,  Bb, Wt, tid); __syncthreads();
    r4stage<64, false>(Bb, A,  Wt, tid); __syncthreads();
    r4stage<256,false>(A,  Bb, Wt, tid); __syncthreads();

    // Hermitian unpack + H + product:
    //   A_cc = (P + conj(Q))/2,  F = (P - conj(Q))/(2i),  Q = P[N-i]
    //   H = 10^(A_cc.re/10) * exp(i*A_cc.im) * (1/1024)
    //   G = conj(F) * H
    const float LOG2_10_DIV10 = 0.33219280948873623f;
    #pragma unroll
    for (int r = 0; r < 4; ++r){
        int i = tid + (r << 8);
        float2 P = Bb[PHI(i)];
        float2 Q = Bb[PHI((1024 - i) & 1023)];
        float Are = 0.5f * (P.x + Q.x);
        float Aim = 0.5f * (P.y - Q.y);
        float Fx  = 0.5f * (P.y + Q.y);
        float Fy  = 0.5f * (Q.x - P.x);
        float mag = exp2f(Are * LOG2_10_DIV10) * (1.0f/1024.0f);
        float s, c;
        sincosf(Aim, &s, &c);
        float Hx = mag * c, Hy = mag * s;
        A[PHI(i)] = make_float2(Fx*Hx + Fy*Hy, Fx*Hy - Fy*Hx);
    }
    __syncthreads();

    // inverse FFT, result in Bb; y[m] = Re(Bb[m]) = circular xcorr of frame with imp
    r4stage<1,  true>(A,  Bb, Wt, tid); __syncthreads();
    r4stage<4,  true>(Bb, A,  Wt, tid); __syncthreads();
    r4stage<16, true>(A,  Bb, Wt, tid); __syncthreads();
    r4stage<64, true>(Bb, A,  Wt, tid); __syncthreads();
    r4stage<256,true>(A,  Bb, Wt, tid); __syncthreads();

    // zw[n] = y[511-n] * hann[n]
    float* zrow = &zw[(size_t)(b*T_LEN + t)*512];
    #pragma unroll
    for (int r = 0; r < 2; ++r){
        int n = tid + (r << 8);
        float yv = Bb[PHI(511 - n)].x;
        float wv = 0.5f * (1.0f - __cosf(PI2 * (float)n * (1.0f/512.0f)));
        zrow[n] = yv * wv;
    }
}

// -------- OLA + clip --------
__global__ __launch_bounds__(256) void k_ola(const float* __restrict__ zw,
                                             float* __restrict__ out){
    const int t = blockIdx.x;
    const int b = blockIdx.y;
    const int h = threadIdx.x;
    const int tm = (t + T_LEN - 1) % T_LEN;
    float v = zw[(size_t)(b*T_LEN + t)*512 + h]
            + zw[(size_t)(b*T_LEN + tm)*512 + 256 + h];
    v = fminf(fmaxf(v, -1.0f), 1.0f);
    out[(size_t)b*ZLEN + t*HOPSZ + h] = v;
}

extern "C" void kernel_launch(void* const* d_in, const int* in_sizes, int n_in,
                              void* d_out, int out_size, void* d_ws, size_t ws_size,
                              hipStream_t stream){
    const float* x  = (const float*)d_in[0];
    const float* z  = (const float*)d_in[1];
    const float* W1 = (const float*)d_in[2];
    const float* b1 = (const float*)d_in[3];
    const float* W2 = (const float*)d_in[4];
    const float* b2 = (const float*)d_in[5];
    const float* W3 = (const float*)d_in[6];
    const float* b3 = (const float*)d_in[7];
    const float* W4 = (const float*)d_in[8];
    const float* b4 = (const float*)d_in[9];
    float* out = (float*)d_out;
    float* ws  = (float*)d_ws;

    float* h1   = ws;                 // 3,276,800 floats
    float* h2   = ws + 3276800;       // 3,276,800 floats (ccep overlays this)
    float* ccep = h2;
    float* zwb  = ws + 6553600;       // 6,553,600 floats

    dim3 blk(256);
    dim3 gconv(T_LEN/16, B_SZ);       // (50,16)
    dim3 gf(T_LEN, B_SZ);             // (800,16)

    k_conv1<<<gconv, blk, 0, stream>>>(x, W1, b1, h1);
    k_convg<<<gconv, blk, 0, stream>>>(h1, W2, b2, h2);
    k_convg<<<gconv, blk, 0, stream>>>(h2, W3, b3, h1);
    k_conv4<<<gconv, blk, 0, stream>>>(h1, W4, b4, ccep);
    k_filter<<<gf, blk, 0, stream>>>(ccep, z, zwb);
    k_ola<<<gf, blk, 0, stream>>>(zwb, out);
}

// Round 4
// 261.081 us; speedup vs baseline: 1.9251x; 1.1218x over previous
//
#include <hip/hip_runtime.h>

#define T_LEN 800
#define B_SZ  16
#define D_IN  80
#define CCH   256
#define OUT_CH 222
#define HOPSZ 256
#define WINSZ 512
#define NFFT  1024
#define ZLEN  (T_LEN*HOPSZ)   // 204800
#define CSTRIDE 224           // padded ccep row stride
#define W4STR 224             // padded co stride for W4_t

#define PHI(i) ((i) + ((i)>>3))   // pad 1 per 8 complex: conflict-free strides

__device__ __forceinline__ float2 cmul(float2 a, float2 b){
    return make_float2(a.x*b.x - a.y*b.y, a.x*b.y + a.y*b.x);
}

// -------- weight transpose: [co][ci][d] -> [ci][d][co] (coalesced conv reads) --------
__global__ __launch_bounds__(256) void k_wtrans(const float* __restrict__ W1,
                                                const float* __restrict__ W2,
                                                const float* __restrict__ W3,
                                                const float* __restrict__ W4,
                                                float* __restrict__ w1t,
                                                float* __restrict__ w2t,
                                                float* __restrict__ w3t,
                                                float* __restrict__ w4t){
    const int i = blockIdx.x*256 + threadIdx.x;
    switch (blockIdx.y){
    case 0: if (i < 80*3*256){
        int co = i & 255, r = i >> 8, ci = r/3, d = r - 3*ci;
        w1t[i] = W1[(co*80 + ci)*3 + d];
    } break;
    case 1: if (i < 32*3*256){
        int co = i & 255, r = i >> 8, cil = r/3, d = r - 3*cil;
        w2t[i] = W2[(co*32 + cil)*3 + d];
    } break;
    case 2: if (i < 32*3*256){
        int co = i & 255, r = i >> 8, cil = r/3, d = r - 3*cil;
        w3t[i] = W3[(co*32 + cil)*3 + d];
    } break;
    default: if (i < 256*3*W4STR){
        int co = i % W4STR, r = i / W4STR, ci = r/3, d = r - 3*ci;
        w4t[i] = (co < OUT_CH) ? W4[(co*256 + ci)*3 + d] : 0.f;
    } break;
    }
}

// -------- conv1: x (B,T,80) -> h1 (B,T,256), relu --------
__global__ __launch_bounds__(256) void k_conv1(const float* __restrict__ x,
                                               const float* __restrict__ Wt,
                                               const float* __restrict__ bias,
                                               float* __restrict__ out){
    __shared__ __align__(16) float xs[80*20];
    const int t0 = blockIdx.x * 16;
    const int b  = blockIdx.y;
    const int tid = threadIdx.x;
    for (int i = tid; i < 80*18; i += 256){
        int tt = i / 80, ci = i - tt*80;
        int t = t0 - 1 + tt;
        xs[ci*20 + tt] = (t >= 0 && t < T_LEN) ? x[(b*T_LEN + t)*D_IN + ci] : 0.f;
    }
    __syncthreads();
    const int co = tid;
    float acc[16];
    float bv = bias[co];
    #pragma unroll
    for (int t = 0; t < 16; ++t) acc[t] = bv;
    for (int ci = 0; ci < 80; ++ci){
        float w0 = Wt[ci*768 + co];
        float w1 = Wt[ci*768 + 256 + co];
        float w2 = Wt[ci*768 + 512 + co];
        const float* xp = &xs[ci*20];
        float xr[18];
        #pragma unroll
        for (int q = 0; q < 4; ++q){
            float4 v = *(const float4*)(xp + 4*q);
            xr[4*q] = v.x; xr[4*q+1] = v.y; xr[4*q+2] = v.z; xr[4*q+3] = v.w;
        }
        { float2 v = *(const float2*)(xp + 16); xr[16] = v.x; xr[17] = v.y; }
        #pragma unroll
        for (int t = 0; t < 16; ++t)
            acc[t] += xr[t]*w0 + xr[t+1]*w1 + xr[t+2]*w2;
    }
    #pragma unroll
    for (int t = 0; t < 16; ++t)
        out[(b*T_LEN + t0 + t)*CCH + co] = fmaxf(acc[t], 0.f);
}

// -------- grouped conv (256->256, groups=8, Cin_g=32), relu --------
__global__ __launch_bounds__(256) void k_convg(const float* __restrict__ in,
                                               const float* __restrict__ Wt,
                                               const float* __restrict__ bias,
                                               float* __restrict__ out){
    __shared__ __align__(16) float hs[256*20];
    const int t0 = blockIdx.x * 16;
    const int b  = blockIdx.y;
    const int tid = threadIdx.x;
    for (int i = tid; i < 256*18; i += 256){
        int tt = i >> 8, ci = i & 255;
        int t = t0 - 1 + tt;
        hs[ci*20 + tt] = (t >= 0 && t < T_LEN) ? in[(b*T_LEN + t)*CCH + ci] : 0.f;
    }
    __syncthreads();
    const int co = tid;
    const int cbase = (co >> 5) << 5;
    float acc[16];
    float bv = bias[co];
    #pragma unroll
    for (int t = 0; t < 16; ++t) acc[t] = bv;
    for (int cil = 0; cil < 32; ++cil){
        float w0 = Wt[cil*768 + co];
        float w1 = Wt[cil*768 + 256 + co];
        float w2 = Wt[cil*768 + 512 + co];
        const float* xp = &hs[(cbase + cil)*20];
        float xr[18];
        #pragma unroll
        for (int q = 0; q < 4; ++q){
            float4 v = *(const float4*)(xp + 4*q);
            xr[4*q] = v.x; xr[4*q+1] = v.y; xr[4*q+2] = v.z; xr[4*q+3] = v.w;
        }
        { float2 v = *(const float2*)(xp + 16); xr[16] = v.x; xr[17] = v.y; }
        #pragma unroll
        for (int t = 0; t < 16; ++t)
            acc[t] += xr[t]*w0 + xr[t+1]*w1 + xr[t+2]*w2;
    }
    #pragma unroll
    for (int t = 0; t < 16; ++t)
        out[(b*T_LEN + t0 + t)*CCH + co] = fmaxf(acc[t], 0.f);
}

// -------- conv4 (256->222) + divide by quefrency; t-tile 8 --------
__global__ __launch_bounds__(256) void k_conv4(const float* __restrict__ in,
                                               const float* __restrict__ Wt,
                                               const float* __restrict__ bias,
                                               float* __restrict__ ccep){
    __shared__ __align__(16) float hs[256*12];   // 10 t-values, stride 12
    const int t0 = blockIdx.x * 8;
    const int b  = blockIdx.y;
    const int tid = threadIdx.x;
    for (int i = tid; i < 256*10; i += 256){
        int tt = i >> 8, ci = i & 255;
        int t = t0 - 1 + tt;
        hs[ci*12 + tt] = (t >= 0 && t < T_LEN) ? in[(b*T_LEN + t)*CCH + ci] : 0.f;
    }
    __syncthreads();
    const int co = tid;
    if (co >= OUT_CH) return;
    float acc[8];
    float bv = bias[co];
    #pragma unroll
    for (int t = 0; t < 8; ++t) acc[t] = bv;
    for (int ci = 0; ci < 256; ++ci){
        float w0 = Wt[ci*(3*W4STR) + co];
        float w1 = Wt[ci*(3*W4STR) + W4STR + co];
        float w2 = Wt[ci*(3*W4STR) + 2*W4STR + co];
        const float* xp = &hs[ci*12];
        float xr[10];
        #pragma unroll
        for (int q = 0; q < 2; ++q){
            float4 v = *(const float4*)(xp + 4*q);
            xr[4*q] = v.x; xr[4*q+1] = v.y; xr[4*q+2] = v.z; xr[4*q+3] = v.w;
        }
        { float2 v = *(const float2*)(xp + 8); xr[8] = v.x; xr[9] = v.y; }
        #pragma unroll
        for (int t = 0; t < 8; ++t)
            acc[t] += xr[t]*w0 + xr[t+1]*w1 + xr[t+2]*w2;
    }
    float q = (co < 111) ? (float)(111 - co) : (float)(co - 110);
    float invq = 1.0f / q;
    #pragma unroll
    for (int t = 0; t < 8; ++t)
        ccep[(b*T_LEN + t0 + t)*CSTRIDE + co] = acc[t] * invq;
}

// -------- radix-4 Stockham stage: 256 threads, one j each --------
template<int Ns, bool INV>
__device__ __forceinline__ void r4stage(const float2* __restrict__ src,
                                        float2* __restrict__ dst,
                                        const float2* __restrict__ Wt,
                                        int j){
    const int jm = j & (Ns - 1);
    float2 v0 = src[PHI(j)];
    float2 v1 = src[PHI(j + 256)];
    float2 v2 = src[PHI(j + 512)];
    float2 v3 = src[PHI(j + 768)];
    if (Ns > 1){
        float2 w1 = Wt[PHI(jm * (256 / Ns))];
        if (INV) w1.y = -w1.y;
        float2 w2 = cmul(w1, w1);
        float2 w3 = cmul(w2, w1);
        v1 = cmul(v1, w1);
        v2 = cmul(v2, w2);
        v3 = cmul(v3, w3);
    }
    float2 t0 = make_float2(v0.x + v2.x, v0.y + v2.y);
    float2 t1 = make_float2(v0.x - v2.x, v0.y - v2.y);
    float2 t2 = make_float2(v1.x + v3.x, v1.y + v3.y);
    float2 t3 = make_float2(v1.x - v3.x, v1.y - v3.y);
    float2 o0 = make_float2(t0.x + t2.x, t0.y + t2.y);
    float2 o2 = make_float2(t0.x - t2.x, t0.y - t2.y);
    float2 o1, o3;
    if (!INV){ // -i*t3
        o1 = make_float2(t1.x + t3.y, t1.y - t3.x);
        o3 = make_float2(t1.x - t3.y, t1.y + t3.x);
    } else {   // +i*t3
        o1 = make_float2(t1.x - t3.y, t1.y + t3.x);
        o3 = make_float2(t1.x + t3.y, t1.y - t3.x);
    }
    const int base = ((j - jm) << 2) + jm;
    dst[PHI(base)]          = o0;
    dst[PHI(base + Ns)]     = o1;
    dst[PHI(base + 2*Ns)]   = o2;
    dst[PHI(base + 3*Ns)]   = o3;
}

// -------- per-(b,t): packed FFT(ccep,frame) -> G = conj(F)*H -> IFFT -> window --------
__global__ __launch_bounds__(256) void k_filter(const float* __restrict__ ccep,
                                                const float* __restrict__ z,
                                                float* __restrict__ zw){
    __shared__ __align__(16) float2 A[1152];
    __shared__ __align__(16) float2 Bb[1152];
    __shared__ __align__(16) float2 Wt[288];
    const int t = blockIdx.x;
    const int b = blockIdx.y;
    const int tid = threadIdx.x;
    const float PI2 = 6.283185307179586f;

    {
        float s, c;
        sincosf(-PI2 * (float)tid * (1.0f/1024.0f), &s, &c);
        Wt[PHI(tid)] = make_float2(c, s);
    }
    const float* crow = &ccep[(b*T_LEN + t)*CSTRIDE];
    #pragma unroll
    for (int r = 0; r < 4; ++r){
        int i = tid + (r << 8);
        float av = (i >= 401 && i < 623) ? crow[i - 401] : 0.f;
        float fv = 0.f;
        if (i < 512){
            int zi = t*HOPSZ + i - 255;
            fv = (zi >= 0 && zi < ZLEN) ? z[b*ZLEN + zi] : 0.f;
        }
        A[PHI(i)] = make_float2(av, fv);
    }
    __syncthreads();

    r4stage<1,  false>(A,  Bb, Wt, tid); __syncthreads();
    r4stage<4,  false>(Bb, A,  Wt, tid); __syncthreads();
    r4stage<16, false>(A,  Bb, Wt, tid); __syncthreads();
    r4stage<64, false>(Bb, A,  Wt, tid); __syncthreads();
    r4stage<256,false>(A,  Bb, Wt, tid); __syncthreads();

    const float LOG2_10_DIV10 = 0.33219280948873623f;
    #pragma unroll
    for (int r = 0; r < 4; ++r){
        int i = tid + (r << 8);
        float2 P = Bb[PHI(i)];
        float2 Q = Bb[PHI((1024 - i) & 1023)];
        float Are = 0.5f * (P.x + Q.x);
        float Aim = 0.5f * (P.y - Q.y);
        float Fx  = 0.5f * (P.y + Q.y);
        float Fy  = 0.5f * (Q.x - P.x);
        float mag = exp2f(Are * LOG2_10_DIV10) * (1.0f/1024.0f);
        float s, c;
        sincosf(Aim, &s, &c);
        float Hx = mag * c, Hy = mag * s;
        A[PHI(i)] = make_float2(Fx*Hx + Fy*Hy, Fx*Hy - Fy*Hx);
    }
    __syncthreads();

    r4stage<1,  true>(A,  Bb, Wt, tid); __syncthreads();
    r4stage<4,  true>(Bb, A,  Wt, tid); __syncthreads();
    r4stage<16, true>(A,  Bb, Wt, tid); __syncthreads();
    r4stage<64, true>(Bb, A,  Wt, tid); __syncthreads();
    r4stage<256,true>(A,  Bb, Wt, tid); __syncthreads();

    float* zrow = &zw[(size_t)(b*T_LEN + t)*512];
    #pragma unroll
    for (int r = 0; r < 2; ++r){
        int n = tid + (r << 8);
        float yv = Bb[PHI(511 - n)].x;
        float wv = 0.5f * (1.0f - __cosf(PI2 * (float)n * (1.0f/512.0f)));
        zrow[n] = yv * wv;
    }
}

// -------- OLA + clip --------
__global__ __launch_bounds__(256) void k_ola(const float* __restrict__ zw,
                                             float* __restrict__ out){
    const int t = blockIdx.x;
    const int b = blockIdx.y;
    const int h = threadIdx.x;
    const int tm = (t + T_LEN - 1) % T_LEN;
    float v = zw[(size_t)(b*T_LEN + t)*512 + h]
            + zw[(size_t)(b*T_LEN + tm)*512 + 256 + h];
    v = fminf(fmaxf(v, -1.0f), 1.0f);
    out[(size_t)b*ZLEN + t*HOPSZ + h] = v;
}

extern "C" void kernel_launch(void* const* d_in, const int* in_sizes, int n_in,
                              void* d_out, int out_size, void* d_ws, size_t ws_size,
                              hipStream_t stream){
    const float* x  = (const float*)d_in[0];
    const float* z  = (const float*)d_in[1];
    const float* W1 = (const float*)d_in[2];
    const float* b1 = (const float*)d_in[3];
    const float* W2 = (const float*)d_in[4];
    const float* b2 = (const float*)d_in[5];
    const float* W3 = (const float*)d_in[6];
    const float* b3 = (const float*)d_in[7];
    const float* W4 = (const float*)d_in[8];
    const float* b4 = (const float*)d_in[9];
    float* out = (float*)d_out;
    float* ws  = (float*)d_ws;

    float* h1   = ws;                 // 3,276,800 floats
    float* h2   = ws + 3276800;       // 3,276,800 floats (ccep overlays this)
    float* ccep = h2;
    float* zwb  = ws + 6553600;       // 6,553,600 floats
    // transposed weights live in the FRONT of zwb: read only by convs,
    // overwritten later by k_filter (stream-ordered, safe, no extra ws)
    float* w1t  = zwb;                // 61,440
    float* w2t  = zwb + 61440;        // 24,576
    float* w3t  = zwb + 86016;        // 24,576
    float* w4t  = zwb + 110592;       // 172,032 (ends at 282,624)

    dim3 blk(256);
    dim3 gwt(672, 4);                 // covers largest tensor (172,032 elems)
    dim3 gconv(T_LEN/16, B_SZ);       // (50,16)
    dim3 gconv4(T_LEN/8, B_SZ);      // (100,16)
    dim3 gf(T_LEN, B_SZ);             // (800,16)

    k_wtrans<<<gwt, blk, 0, stream>>>(W1, W2, W3, W4, w1t, w2t, w3t, w4t);
    k_conv1<<<gconv, blk, 0, stream>>>(x, w1t, b1, h1);
    k_convg<<<gconv, blk, 0, stream>>>(h1, w2t, b2, h2);
    k_convg<<<gconv, blk, 0, stream>>>(h2, w3t, b3, h1);
    k_conv4<<<gconv4, blk, 0, stream>>>(h1, w4t, b4, ccep);
    k_filter<<<gf, blk, 0, stream>>>(ccep, z, zwb);
    k_ola<<<gf, blk, 0, stream>>>(zwb, out);
}

// Round 5
// 242.793 us; speedup vs baseline: 2.0702x; 1.0753x over previous
//
#include <hip/hip_runtime.h>

#define T_LEN 800
#define B_SZ  16
#define D_IN  80
#define CCH   256
#define OUT_CH 222
#define HOPSZ 256
#define WINSZ 512
#define NFFT  1024
#define ZLEN  (T_LEN*HOPSZ)   // 204800
#define CSTRIDE 256           // padded ccep row stride
#define W4STR 256             // padded co stride for W4_t

#define PHI(i) ((i) + ((i)>>3))   // pad 1 per 8 complex: conflict-free strides

__device__ __forceinline__ float2 cmul(float2 a, float2 b){
    return make_float2(a.x*b.x - a.y*b.y, a.x*b.y + a.y*b.x);
}

// -------- weight transpose: [co][ci][d] -> [ci][d][co] (coalesced conv reads) --------
__global__ __launch_bounds__(256) void k_wtrans(const float* __restrict__ W1,
                                                const float* __restrict__ W2,
                                                const float* __restrict__ W3,
                                                const float* __restrict__ W4,
                                                float* __restrict__ w1t,
                                                float* __restrict__ w2t,
                                                float* __restrict__ w3t,
                                                float* __restrict__ w4t){
    const int i = blockIdx.x*256 + threadIdx.x;
    switch (blockIdx.y){
    case 0: if (i < 80*3*256){
        int co = i & 255, r = i >> 8, ci = r/3, d = r - 3*ci;
        w1t[i] = W1[(co*80 + ci)*3 + d];
    } break;
    case 1: if (i < 32*3*256){
        int co = i & 255, r = i >> 8, cil = r/3, d = r - 3*cil;
        w2t[i] = W2[(co*32 + cil)*3 + d];
    } break;
    case 2: if (i < 32*3*256){
        int co = i & 255, r = i >> 8, cil = r/3, d = r - 3*cil;
        w3t[i] = W3[(co*32 + cil)*3 + d];
    } break;
    default: if (i < 256*3*W4STR){
        int co = i & 255, r = i >> 8, ci = r/3, d = r - 3*ci;
        w4t[i] = (co < OUT_CH) ? W4[(co*256 + ci)*3 + d] : 0.f;
    } break;
    }
}

// -------- conv1: x (B,T,80) -> h1 (B,T,256), relu --------
__global__ __launch_bounds__(256) void k_conv1(const float* __restrict__ x,
                                               const float* __restrict__ Wt,
                                               const float* __restrict__ bias,
                                               float* __restrict__ out){
    __shared__ __align__(16) float xs[80*20];
    const int t0 = blockIdx.x * 16;
    const int b  = blockIdx.y;
    const int tid = threadIdx.x;
    for (int i = tid; i < 80*18; i += 256){
        int tt = i / 80, ci = i - tt*80;
        int t = t0 - 1 + tt;
        xs[ci*20 + tt] = (t >= 0 && t < T_LEN) ? x[(b*T_LEN + t)*D_IN + ci] : 0.f;
    }
    __syncthreads();
    const int co = tid;
    float acc[16];
    float bv = bias[co];
    #pragma unroll
    for (int t = 0; t < 16; ++t) acc[t] = bv;
    const float* wp = Wt + co;
    for (int ci = 0; ci < 80; ++ci){
        float w0 = wp[0], w1 = wp[256], w2 = wp[512];
        wp += 768;
        const float* xp = &xs[ci*20];
        float4 v0 = *(const float4*)(xp);
        float4 v1 = *(const float4*)(xp + 4);
        float4 v2 = *(const float4*)(xp + 8);
        float4 v3 = *(const float4*)(xp + 12);
        float2 v4 = *(const float2*)(xp + 16);
        float xr[18] = {v0.x,v0.y,v0.z,v0.w, v1.x,v1.y,v1.z,v1.w,
                        v2.x,v2.y,v2.z,v2.w, v3.x,v3.y,v3.z,v3.w, v4.x,v4.y};
        #pragma unroll
        for (int t = 0; t < 16; ++t){
            acc[t] = fmaf(xr[t],   w0, acc[t]);
            acc[t] = fmaf(xr[t+1], w1, acc[t]);
            acc[t] = fmaf(xr[t+2], w2, acc[t]);
        }
    }
    #pragma unroll
    for (int t = 0; t < 16; ++t)
        out[(b*T_LEN + t0 + t)*CCH + co] = fmaxf(acc[t], 0.f);
}

// -------- grouped conv (256->256, groups=8, Cin_g=32), relu --------
__global__ __launch_bounds__(256) void k_convg(const float* __restrict__ in,
                                               const float* __restrict__ Wt,
                                               const float* __restrict__ bias,
                                               float* __restrict__ out){
    __shared__ __align__(16) float hs[256*20];
    const int t0 = blockIdx.x * 16;
    const int b  = blockIdx.y;
    const int tid = threadIdx.x;
    for (int i = tid; i < 256*18; i += 256){
        int tt = i >> 8, ci = i & 255;
        int t = t0 - 1 + tt;
        hs[ci*20 + tt] = (t >= 0 && t < T_LEN) ? in[(b*T_LEN + t)*CCH + ci] : 0.f;
    }
    __syncthreads();
    const int co = tid;
    const int cbase = (co >> 5) << 5;
    float acc[16];
    float bv = bias[co];
    #pragma unroll
    for (int t = 0; t < 16; ++t) acc[t] = bv;
    const float* wp = Wt + co;
    for (int cil = 0; cil < 32; ++cil){
        float w0 = wp[0], w1 = wp[256], w2 = wp[512];
        wp += 768;
        const float* xp = &hs[(cbase + cil)*20];
        float4 v0 = *(const float4*)(xp);
        float4 v1 = *(const float4*)(xp + 4);
        float4 v2 = *(const float4*)(xp + 8);
        float4 v3 = *(const float4*)(xp + 12);
        float2 v4 = *(const float2*)(xp + 16);
        float xr[18] = {v0.x,v0.y,v0.z,v0.w, v1.x,v1.y,v1.z,v1.w,
                        v2.x,v2.y,v2.z,v2.w, v3.x,v3.y,v3.z,v3.w, v4.x,v4.y};
        #pragma unroll
        for (int t = 0; t < 16; ++t){
            acc[t] = fmaf(xr[t],   w0, acc[t]);
            acc[t] = fmaf(xr[t+1], w1, acc[t]);
            acc[t] = fmaf(xr[t+2], w2, acc[t]);
        }
    }
    #pragma unroll
    for (int t = 0; t < 16; ++t)
        out[(b*T_LEN + t0 + t)*CCH + co] = fmaxf(acc[t], 0.f);
}

// -------- conv4 (256->256 padded from 222) + divide by quefrency; t-tile 16 --------
__global__ __launch_bounds__(256) void k_conv4(const float* __restrict__ in,
                                               const float* __restrict__ Wt,
                                               const float* __restrict__ bias,
                                               float* __restrict__ ccep){
    __shared__ __align__(16) float hs[256*20];
    const int t0 = blockIdx.x * 16;
    const int b  = blockIdx.y;
    const int tid = threadIdx.x;
    for (int i = tid; i < 256*18; i += 256){
        int tt = i >> 8, ci = i & 255;
        int t = t0 - 1 + tt;
        hs[ci*20 + tt] = (t >= 0 && t < T_LEN) ? in[(b*T_LEN + t)*CCH + ci] : 0.f;
    }
    __syncthreads();
    const int co = tid;
    float acc[16];
    float bv = (co < OUT_CH) ? bias[co] : 0.f;
    #pragma unroll
    for (int t = 0; t < 16; ++t) acc[t] = bv;
    const float* wp = Wt + co;
    for (int ci = 0; ci < 256; ++ci){
        float w0 = wp[0], w1 = wp[256], w2 = wp[512];
        wp += 768;
        const float* xp = &hs[ci*20];
        float4 v0 = *(const float4*)(xp);
        float4 v1 = *(const float4*)(xp + 4);
        float4 v2 = *(const float4*)(xp + 8);
        float4 v3 = *(const float4*)(xp + 12);
        float2 v4 = *(const float2*)(xp + 16);
        float xr[18] = {v0.x,v0.y,v0.z,v0.w, v1.x,v1.y,v1.z,v1.w,
                        v2.x,v2.y,v2.z,v2.w, v3.x,v3.y,v3.z,v3.w, v4.x,v4.y};
        #pragma unroll
        for (int t = 0; t < 16; ++t){
            acc[t] = fmaf(xr[t],   w0, acc[t]);
            acc[t] = fmaf(xr[t+1], w1, acc[t]);
            acc[t] = fmaf(xr[t+2], w2, acc[t]);
        }
    }
    float q = (co < 111) ? (float)(111 - co) : (float)(co - 110);
    float invq = 1.0f / q;
    #pragma unroll
    for (int t = 0; t < 16; ++t)
        ccep[(b*T_LEN + t0 + t)*CSTRIDE + co] = acc[t] * invq;
}

// -------- radix-4 Stockham stage: 256 threads, one j each --------
template<int Ns, bool INV>
__device__ __forceinline__ void r4stage(const float2* __restrict__ src,
                                        float2* __restrict__ dst,
                                        const float2* __restrict__ Wt,
                                        int j){
    const int jm = j & (Ns - 1);
    float2 v0 = src[PHI(j)];
    float2 v1 = src[PHI(j + 256)];
    float2 v2 = src[PHI(j + 512)];
    float2 v3 = src[PHI(j + 768)];
    if (Ns > 1){
        float2 w1 = Wt[PHI(jm * (256 / Ns))];
        if (INV) w1.y = -w1.y;
        float2 w2 = cmul(w1, w1);
        float2 w3 = cmul(w2, w1);
        v1 = cmul(v1, w1);
        v2 = cmul(v2, w2);
        v3 = cmul(v3, w3);
    }
    float2 t0 = make_float2(v0.x + v2.x, v0.y + v2.y);
    float2 t1 = make_float2(v0.x - v2.x, v0.y - v2.y);
    float2 t2 = make_float2(v1.x + v3.x, v1.y + v3.y);
    float2 t3 = make_float2(v1.x - v3.x, v1.y - v3.y);
    float2 o0 = make_float2(t0.x + t2.x, t0.y + t2.y);
    float2 o2 = make_float2(t0.x - t2.x, t0.y - t2.y);
    float2 o1, o3;
    if (!INV){ // -i*t3
        o1 = make_float2(t1.x + t3.y, t1.y - t3.x);
        o3 = make_float2(t1.x - t3.y, t1.y + t3.x);
    } else {   // +i*t3
        o1 = make_float2(t1.x - t3.y, t1.y + t3.x);
        o3 = make_float2(t1.x + t3.y, t1.y - t3.x);
    }
    const int base = ((j - jm) << 2) + jm;
    dst[PHI(base)]          = o0;
    dst[PHI(base + Ns)]     = o1;
    dst[PHI(base + 2*Ns)]   = o2;
    dst[PHI(base + 3*Ns)]   = o3;
}

// -------- per-(b,t): packed FFT(ccep,frame) -> G = conj(F)*H -> IFFT -> window --------
__global__ __launch_bounds__(256) void k_filter(const float* __restrict__ ccep,
                                                const float* __restrict__ z,
                                                float* __restrict__ zw){
    __shared__ __align__(16) float2 A[1152];
    __shared__ __align__(16) float2 Bb[1152];
    __shared__ __align__(16) float2 Wt[288];
    const int t = blockIdx.x;
    const int b = blockIdx.y;
    const int tid = threadIdx.x;
    const float PI2 = 6.283185307179586f;

    {
        float s, c;
        __sincosf(-PI2 * (float)tid * (1.0f/1024.0f), &s, &c);
        Wt[PHI(tid)] = make_float2(c, s);
    }
    const float* crow = &ccep[(b*T_LEN + t)*CSTRIDE];
    #pragma unroll
    for (int r = 0; r < 4; ++r){
        int i = tid + (r << 8);
        float av = (i >= 401 && i < 623) ? crow[i - 401] : 0.f;
        float fv = 0.f;
        if (i < 512){
            int zi = t*HOPSZ + i - 255;
            fv = (zi >= 0 && zi < ZLEN) ? z[b*ZLEN + zi] : 0.f;
        }
        A[PHI(i)] = make_float2(av, fv);
    }
    __syncthreads();

    r4stage<1,  false>(A,  Bb, Wt, tid); __syncthreads();
    r4stage<4,  false>(Bb, A,  Wt, tid); __syncthreads();
    r4stage<16, false>(A,  Bb, Wt, tid); __syncthreads();
    r4stage<64, false>(Bb, A,  Wt, tid); __syncthreads();
    r4stage<256,false>(A,  Bb, Wt, tid); __syncthreads();

    const float LOG2_10_DIV10 = 0.33219280948873623f;
    #pragma unroll
    for (int r = 0; r < 4; ++r){
        int i = tid + (r << 8);
        float2 P = Bb[PHI(i)];
        float2 Q = Bb[PHI((1024 - i) & 1023)];
        float Are = 0.5f * (P.x + Q.x);
        float Aim = 0.5f * (P.y - Q.y);
        float Fx  = 0.5f * (P.y + Q.y);
        float Fy  = 0.5f * (Q.x - P.x);
        float mag = exp2f(Are * LOG2_10_DIV10) * (1.0f/1024.0f);
        float s, c;
        sincosf(Aim, &s, &c);
        float Hx = mag * c, Hy = mag * s;
        A[PHI(i)] = make_float2(Fx*Hx + Fy*Hy, Fx*Hy - Fy*Hx);
    }
    __syncthreads();

    r4stage<1,  true>(A,  Bb, Wt, tid); __syncthreads();
    r4stage<4,  true>(Bb, A,  Wt, tid); __syncthreads();
    r4stage<16, true>(A,  Bb, Wt, tid); __syncthreads();
    r4stage<64, true>(Bb, A,  Wt, tid); __syncthreads();
    r4stage<256,true>(A,  Bb, Wt, tid); __syncthreads();

    float* zrow = &zw[(size_t)(b*T_LEN + t)*512];
    #pragma unroll
    for (int r = 0; r < 2; ++r){
        int n = tid + (r << 8);
        float yv = Bb[PHI(511 - n)].x;
        float wv = 0.5f * (1.0f - __cosf(PI2 * (float)n * (1.0f/512.0f)));
        zrow[n] = yv * wv;
    }
}

// -------- OLA + clip --------
__global__ __launch_bounds__(256) void k_ola(const float* __restrict__ zw,
                                             float* __restrict__ out){
    const int t = blockIdx.x;
    const int b = blockIdx.y;
    const int h = threadIdx.x;
    const int tm = (t + T_LEN - 1) % T_LEN;
    float v = zw[(size_t)(b*T_LEN + t)*512 + h]
            + zw[(size_t)(b*T_LEN + tm)*512 + 256 + h];
    v = fminf(fmaxf(v, -1.0f), 1.0f);
    out[(size_t)b*ZLEN + t*HOPSZ + h] = v;
}

extern "C" void kernel_launch(void* const* d_in, const int* in_sizes, int n_in,
                              void* d_out, int out_size, void* d_ws, size_t ws_size,
                              hipStream_t stream){
    const float* x  = (const float*)d_in[0];
    const float* z  = (const float*)d_in[1];
    const float* W1 = (const float*)d_in[2];
    const float* b1 = (const float*)d_in[3];
    const float* W2 = (const float*)d_in[4];
    const float* b2 = (const float*)d_in[5];
    const float* W3 = (const float*)d_in[6];
    const float* b3 = (const float*)d_in[7];
    const float* W4 = (const float*)d_in[8];
    const float* b4 = (const float*)d_in[9];
    float* out = (float*)d_out;
    float* ws  = (float*)d_ws;

    float* h1   = ws;                 // 3,276,800 floats
    float* h2   = ws + 3276800;       // 3,276,800 floats (ccep overlays this, 12800*256)
    float* ccep = h2;
    float* zwb  = ws + 6553600;       // 6,553,600 floats
    // transposed weights live in the FRONT of zwb: read only by convs,
    // overwritten later by k_filter (stream-ordered, safe, no extra ws)
    float* w1t  = zwb;                // 61,440
    float* w2t  = zwb + 61440;        // 24,576
    float* w3t  = zwb + 86016;        // 24,576
    float* w4t  = zwb + 110592;       // 196,608 (ends at 307,200)

    dim3 blk(256);
    dim3 gwt(768, 4);                 // covers largest tensor (196,608 elems)
    dim3 gconv(T_LEN/16, B_SZ);       // (50,16)
    dim3 gf(T_LEN, B_SZ);             // (800,16)

    k_wtrans<<<gwt, blk, 0, stream>>>(W1, W2, W3, W4, w1t, w2t, w3t, w4t);
    k_conv1<<<gconv, blk, 0, stream>>>(x, w1t, b1, h1);
    k_convg<<<gconv, blk, 0, stream>>>(h1, w2t, b2, h2);
    k_convg<<<gconv, blk, 0, stream>>>(h2, w3t, b3, h1);
    k_conv4<<<gconv, blk, 0, stream>>>(h1, w4t, b4, ccep);
    k_filter<<<gf, blk, 0, stream>>>(ccep, z, zwb);
    k_ola<<<gf, blk, 0, stream>>>(zwb, out);
}

// Round 6
// 235.364 us; speedup vs baseline: 2.1355x; 1.0316x over previous
//
#include <hip/hip_runtime.h>

#define T_LEN 800
#define B_SZ  16
#define D_IN  80
#define CCH   256
#define OUT_CH 222
#define HOPSZ 256
#define WINSZ 512
#define NFFT  1024
#define ZLEN  (T_LEN*HOPSZ)   // 204800
#define CSTRIDE 256           // padded ccep row stride

#define PHI(i) ((i) + ((i)>>3))   // pad 1 per 8 complex: conflict-free strides

__device__ __forceinline__ float2 cmul(float2 a, float2 b){
    return make_float2(a.x*b.x - a.y*b.y, a.x*b.y + a.y*b.x);
}

// -------- weight transpose into float4 [ci][co] = (w0,w1,w2,0) --------
__global__ __launch_bounds__(256) void k_wtrans(const float* __restrict__ W1,
                                                const float* __restrict__ W2,
                                                const float* __restrict__ W3,
                                                const float* __restrict__ W4,
                                                float4* __restrict__ w1t,
                                                float4* __restrict__ w2t,
                                                float4* __restrict__ w3t,
                                                float4* __restrict__ w4t){
    const int i = blockIdx.x*256 + threadIdx.x;
    switch (blockIdx.y){
    case 0: if (i < 80*256){
        int ci = i >> 8, co = i & 255;
        const float* s = &W1[(co*80 + ci)*3];
        w1t[i] = make_float4(s[0], s[1], s[2], 0.f);
    } break;
    case 1: if (i < 32*256){
        int cil = i >> 8, co = i & 255;
        const float* s = &W2[(co*32 + cil)*3];
        w2t[i] = make_float4(s[0], s[1], s[2], 0.f);
    } break;
    case 2: if (i < 32*256){
        int cil = i >> 8, co = i & 255;
        const float* s = &W3[(co*32 + cil)*3];
        w3t[i] = make_float4(s[0], s[1], s[2], 0.f);
    } break;
    default: if (i < 256*256){
        int ci = i >> 8, co = i & 255;
        if (co < OUT_CH){
            const float* s = &W4[(co*256 + ci)*3];
            w4t[i] = make_float4(s[0], s[1], s[2], 0.f);
        } else {
            w4t[i] = make_float4(0.f, 0.f, 0.f, 0.f);
        }
    } break;
    }
}

// -------- conv1: x (B,T,80) -> h1 (B,T,256), relu; co-split z, t-split 2x8 --------
__global__ __launch_bounds__(256) void k_conv1(const float* __restrict__ x,
                                               const float4* __restrict__ Wt,
                                               const float* __restrict__ bias,
                                               float* __restrict__ out){
    __shared__ __align__(16) float xs[80*20];
    const int t0 = blockIdx.x * 16;
    const int b  = blockIdx.y;
    const int tid = threadIdx.x;
    const int co   = (blockIdx.z << 7) | (tid & 127);
    const int toff = (tid >> 7) << 3;
    for (int i = tid; i < 80*18; i += 256){
        int tt = i / 80, ci = i - tt*80;
        int t = t0 - 1 + tt;
        xs[ci*20 + tt] = (t >= 0 && t < T_LEN) ? x[(b*T_LEN + t)*D_IN + ci] : 0.f;
    }
    __syncthreads();
    float acc[8];
    float bv = bias[co];
    #pragma unroll
    for (int t = 0; t < 8; ++t) acc[t] = bv;
    const float4* wp = Wt + co;
    float4 w = *wp;
    for (int ci = 0; ci < 80; ++ci){
        wp += 256;
        float4 wn = *wp;    // prefetch (last overrun lands in adjacent buffer, unused)
        const float* xp = &xs[ci*20 + toff];
        float4 v0 = *(const float4*)(xp);
        float4 v1 = *(const float4*)(xp + 4);
        float2 v2 = *(const float2*)(xp + 8);
        float xr[10] = {v0.x,v0.y,v0.z,v0.w, v1.x,v1.y,v1.z,v1.w, v2.x,v2.y};
        #pragma unroll
        for (int t = 0; t < 8; ++t){
            acc[t] = fmaf(xr[t],   w.x, acc[t]);
            acc[t] = fmaf(xr[t+1], w.y, acc[t]);
            acc[t] = fmaf(xr[t+2], w.z, acc[t]);
        }
        w = wn;
    }
    #pragma unroll
    for (int t = 0; t < 8; ++t)
        out[(b*T_LEN + t0 + toff + t)*CCH + co] = fmaxf(acc[t], 0.f);
}

// -------- grouped conv (256->256, groups=8); co-split z, stages only its 128 ci --------
__global__ __launch_bounds__(256) void k_convg(const float* __restrict__ in,
                                               const float4* __restrict__ Wt,
                                               const float* __restrict__ bias,
                                               float* __restrict__ out){
    __shared__ __align__(16) float hs[128*20];
    const int t0 = blockIdx.x * 16;
    const int b  = blockIdx.y;
    const int tid = threadIdx.x;
    const int z  = blockIdx.z;
    const int co   = (z << 7) | (tid & 127);
    const int toff = (tid >> 7) << 3;
    const int lbase = tid & 96;     // local group base within the 128-ci half
    for (int i = tid; i < 128*18; i += 256){
        int tt = i >> 7, cl = i & 127;
        int t = t0 - 1 + tt;
        hs[cl*20 + tt] = (t >= 0 && t < T_LEN) ? in[(b*T_LEN + t)*CCH + (z << 7) + cl] : 0.f;
    }
    __syncthreads();
    float acc[8];
    float bv = bias[co];
    #pragma unroll
    for (int t = 0; t < 8; ++t) acc[t] = bv;
    const float4* wp = Wt + co;
    float4 w = *wp;
    for (int cil = 0; cil < 32; ++cil){
        wp += 256;
        float4 wn = *wp;
        const float* xp = &hs[(lbase + cil)*20 + toff];
        float4 v0 = *(const float4*)(xp);
        float4 v1 = *(const float4*)(xp + 4);
        float2 v2 = *(const float2*)(xp + 8);
        float xr[10] = {v0.x,v0.y,v0.z,v0.w, v1.x,v1.y,v1.z,v1.w, v2.x,v2.y};
        #pragma unroll
        for (int t = 0; t < 8; ++t){
            acc[t] = fmaf(xr[t],   w.x, acc[t]);
            acc[t] = fmaf(xr[t+1], w.y, acc[t]);
            acc[t] = fmaf(xr[t+2], w.z, acc[t]);
        }
        w = wn;
    }
    #pragma unroll
    for (int t = 0; t < 8; ++t)
        out[(b*T_LEN + t0 + toff + t)*CCH + co] = fmaxf(acc[t], 0.f);
}

// -------- conv4 (256->256 padded) + /quef; co-split z, t-split 2x8 --------
__global__ __launch_bounds__(256) void k_conv4(const float* __restrict__ in,
                                               const float4* __restrict__ Wt,
                                               const float* __restrict__ bias,
                                               float* __restrict__ ccep){
    __shared__ __align__(16) float hs[256*20];
    const int t0 = blockIdx.x * 16;
    const int b  = blockIdx.y;
    const int tid = threadIdx.x;
    const int co   = (blockIdx.z << 7) | (tid & 127);
    const int toff = (tid >> 7) << 3;
    for (int i = tid; i < 256*18; i += 256){
        int tt = i >> 8, ci = i & 255;
        int t = t0 - 1 + tt;
        hs[ci*20 + tt] = (t >= 0 && t < T_LEN) ? in[(b*T_LEN + t)*CCH + ci] : 0.f;
    }
    __syncthreads();
    float acc[8];
    float bv = (co < OUT_CH) ? bias[co] : 0.f;
    #pragma unroll
    for (int t = 0; t < 8; ++t) acc[t] = bv;
    const float4* wp = Wt + co;
    float4 w = *wp;
    for (int ci = 0; ci < 256; ++ci){
        wp += 256;
        float4 wn = *wp;
        const float* xp = &hs[ci*20 + toff];
        float4 v0 = *(const float4*)(xp);
        float4 v1 = *(const float4*)(xp + 4);
        float2 v2 = *(const float2*)(xp + 8);
        float xr[10] = {v0.x,v0.y,v0.z,v0.w, v1.x,v1.y,v1.z,v1.w, v2.x,v2.y};
        #pragma unroll
        for (int t = 0; t < 8; ++t){
            acc[t] = fmaf(xr[t],   w.x, acc[t]);
            acc[t] = fmaf(xr[t+1], w.y, acc[t]);
            acc[t] = fmaf(xr[t+2], w.z, acc[t]);
        }
        w = wn;
    }
    float q = (co < 111) ? (float)(111 - co) : (float)(co - 110);
    float invq = 1.0f / q;
    #pragma unroll
    for (int t = 0; t < 8; ++t)
        ccep[(b*T_LEN + t0 + toff + t)*CSTRIDE + co] = acc[t] * invq;
}

// -------- radix-4 Stockham stage --------
template<int Ns, bool INV>
__device__ __forceinline__ void r4stage(const float2* __restrict__ src,
                                        float2* __restrict__ dst,
                                        const float2* __restrict__ Wt,
                                        int j){
    const int jm = j & (Ns - 1);
    float2 v0 = src[PHI(j)];
    float2 v1 = src[PHI(j + 256)];
    float2 v2 = src[PHI(j + 512)];
    float2 v3 = src[PHI(j + 768)];
    if (Ns > 1){
        float2 w1 = Wt[PHI(jm * (256 / Ns))];
        if (INV) w1.y = -w1.y;
        float2 w2 = cmul(w1, w1);
        float2 w3 = cmul(w2, w1);
        v1 = cmul(v1, w1);
        v2 = cmul(v2, w2);
        v3 = cmul(v3, w3);
    }
    float2 t0 = make_float2(v0.x + v2.x, v0.y + v2.y);
    float2 t1 = make_float2(v0.x - v2.x, v0.y - v2.y);
    float2 t2 = make_float2(v1.x + v3.x, v1.y + v3.y);
    float2 t3 = make_float2(v1.x - v3.x, v1.y - v3.y);
    float2 o0 = make_float2(t0.x + t2.x, t0.y + t2.y);
    float2 o2 = make_float2(t0.x - t2.x, t0.y - t2.y);
    float2 o1, o3;
    if (!INV){
        o1 = make_float2(t1.x + t3.y, t1.y - t3.x);
        o3 = make_float2(t1.x - t3.y, t1.y + t3.x);
    } else {
        o1 = make_float2(t1.x - t3.y, t1.y + t3.x);
        o3 = make_float2(t1.x + t3.y, t1.y - t3.x);
    }
    const int base = ((j - jm) << 2) + jm;
    dst[PHI(base)]          = o0;
    dst[PHI(base + Ns)]     = o1;
    dst[PHI(base + 2*Ns)]   = o2;
    dst[PHI(base + 3*Ns)]   = o3;
}

// -------- per-(b,t): packed FFT(ccep,frame) -> G = conj(F)*H -> IFFT -> window --------
__global__ __launch_bounds__(256) void k_filter(const float* __restrict__ ccep,
                                                const float* __restrict__ z,
                                                float* __restrict__ zw){
    __shared__ __align__(16) float2 A[1152];
    __shared__ __align__(16) float2 Bb[1152];
    __shared__ __align__(16) float2 Wt[288];
    const int t = blockIdx.x;
    const int b = blockIdx.y;
    const int tid = threadIdx.x;
    const float PI2 = 6.283185307179586f;

    {
        float s, c;
        __sincosf(-PI2 * (float)tid * (1.0f/1024.0f), &s, &c);
        Wt[PHI(tid)] = make_float2(c, s);
    }
    const float* crow = &ccep[(b*T_LEN + t)*CSTRIDE];
    #pragma unroll
    for (int r = 0; r < 4; ++r){
        int i = tid + (r << 8);
        float av = (i >= 401 && i < 623) ? crow[i - 401] : 0.f;
        float fv = 0.f;
        if (i < 512){
            int zi = t*HOPSZ + i - 255;
            fv = (zi >= 0 && zi < ZLEN) ? z[b*ZLEN + zi] : 0.f;
        }
        A[PHI(i)] = make_float2(av, fv);
    }
    __syncthreads();

    r4stage<1,  false>(A,  Bb, Wt, tid); __syncthreads();
    r4stage<4,  false>(Bb, A,  Wt, tid); __syncthreads();
    r4stage<16, false>(A,  Bb, Wt, tid); __syncthreads();
    r4stage<64, false>(Bb, A,  Wt, tid); __syncthreads();
    r4stage<256,false>(A,  Bb, Wt, tid); __syncthreads();

    const float LOG2_10_DIV10 = 0.33219280948873623f;
    #pragma unroll
    for (int r = 0; r < 4; ++r){
        int i = tid + (r << 8);
        float2 P = Bb[PHI(i)];
        float2 Q = Bb[PHI((1024 - i) & 1023)];
        float Are = 0.5f * (P.x + Q.x);
        float Aim = 0.5f * (P.y - Q.y);
        float Fx  = 0.5f * (P.y + Q.y);
        float Fy  = 0.5f * (Q.x - P.x);
        float mag = exp2f(Are * LOG2_10_DIV10) * (1.0f/1024.0f);
        float s, c;
        sincosf(Aim, &s, &c);
        float Hx = mag * c, Hy = mag * s;
        A[PHI(i)] = make_float2(Fx*Hx + Fy*Hy, Fx*Hy - Fy*Hx);
    }
    __syncthreads();

    r4stage<1,  true>(A,  Bb, Wt, tid); __syncthreads();
    r4stage<4,  true>(Bb, A,  Wt, tid); __syncthreads();
    r4stage<16, true>(A,  Bb, Wt, tid); __syncthreads();
    r4stage<64, true>(Bb, A,  Wt, tid); __syncthreads();
    r4stage<256,true>(A,  Bb, Wt, tid); __syncthreads();

    float* zrow = &zw[(size_t)(b*T_LEN + t)*512];
    #pragma unroll
    for (int r = 0; r < 2; ++r){
        int n = tid + (r << 8);
        float yv = Bb[PHI(511 - n)].x;
        float wv = 0.5f * (1.0f - __cosf(PI2 * (float)n * (1.0f/512.0f)));
        zrow[n] = yv * wv;
    }
}

// -------- OLA + clip --------
__global__ __launch_bounds__(256) void k_ola(const float* __restrict__ zw,
                                             float* __restrict__ out){
    const int t = blockIdx.x;
    const int b = blockIdx.y;
    const int h = threadIdx.x;
    const int tm = (t + T_LEN - 1) % T_LEN;
    float v = zw[(size_t)(b*T_LEN + t)*512 + h]
            + zw[(size_t)(b*T_LEN + tm)*512 + 256 + h];
    v = fminf(fmaxf(v, -1.0f), 1.0f);
    out[(size_t)b*ZLEN + t*HOPSZ + h] = v;
}

extern "C" void kernel_launch(void* const* d_in, const int* in_sizes, int n_in,
                              void* d_out, int out_size, void* d_ws, size_t ws_size,
                              hipStream_t stream){
    const float* x  = (const float*)d_in[0];
    const float* z  = (const float*)d_in[1];
    const float* W1 = (const float*)d_in[2];
    const float* b1 = (const float*)d_in[3];
    const float* W2 = (const float*)d_in[4];
    const float* b2 = (const float*)d_in[5];
    const float* W3 = (const float*)d_in[6];
    const float* b3 = (const float*)d_in[7];
    const float* W4 = (const float*)d_in[8];
    const float* b4 = (const float*)d_in[9];
    float* out = (float*)d_out;
    float* ws  = (float*)d_ws;

    float* h1   = ws;                 // 3,276,800 floats
    float* h2   = ws + 3276800;       // 3,276,800 floats (ccep overlays, 12800*256)
    float* ccep = h2;
    float* zwb  = ws + 6553600;       // 6,553,600 floats
    // transposed float4 weights in the FRONT of zwb (read only by convs,
    // overwritten later by k_filter — stream-ordered, safe)
    float4* w1t = (float4*)(zwb);               // 20480 float4
    float4* w2t = (float4*)(zwb + 81920);       //  8192 float4
    float4* w3t = (float4*)(zwb + 114688);      //  8192 float4
    float4* w4t = (float4*)(zwb + 147456);      // 65536 float4 (ends @409600 floats)

    dim3 blk(256);
    dim3 gwt(256, 4);
    dim3 gconv(T_LEN/16, B_SZ, 2);    // (50,16,2)
    dim3 gf(T_LEN, B_SZ);             // (800,16)

    k_wtrans<<<gwt, blk, 0, stream>>>(W1, W2, W3, W4, w1t, w2t, w3t, w4t);
    k_conv1<<<gconv, blk, 0, stream>>>(x, w1t, b1, h1);
    k_convg<<<gconv, blk, 0, stream>>>(h1, w2t, b2, h2);
    k_convg<<<gconv, blk, 0, stream>>>(h2, w3t, b3, h1);
    k_conv4<<<gconv, blk, 0, stream>>>(h1, w4t, b4, ccep);
    k_filter<<<gf, blk, 0, stream>>>(ccep, z, zwb);
    k_ola<<<gf, blk, 0, stream>>>(zwb, out);
}